// Round 2
// baseline (770.799 us; speedup 1.0000x reference)
//
#include <hip/hip_runtime.h>

typedef __attribute__((ext_vector_type(8))) short short8;
typedef __attribute__((ext_vector_type(4))) float f32x4;

#define N_NODES 1000000
#define N_UPD   200000
#define D       172
#define BM      32          // rows per block
#define LDA     360         // LDS A row stride in ushorts (720B -> 2-way-free banks)
#define KSTEPS  11          // 11 * 32 = 352 >= 344
#define NTILES  48          // 768 padded N cols / 16
#define NT_W    12          // n-tiles per wave
#define BPACK_USHORTS (KSTEPS*NTILES*64*8)   // 270336
#define BIAS_OFF_BYTES (BPACK_USHORTS*2)     // 540672, 16B aligned

__device__ __forceinline__ unsigned short f2bf(float f) {
  union { float f; unsigned u; } v; v.f = f;
  unsigned r = v.u + 0x7FFFu + ((v.u >> 16) & 1u);
  return (unsigned short)(r >> 16);
}
__device__ __forceinline__ float bf2f(unsigned short h) {
  union { unsigned u; float f; } v; v.u = ((unsigned)h) << 16;
  return v.f;
}

// ---------------------------------------------------------------------------
// Prep: pack B (344x768 virtual, bf16) into MFMA-fragment order + fused biases.
// B col layout: wave w (0..3) owns cols [w*192, w*192+192):
//   [r_pre j=w*48..+48 | z_pre | i_n | h_n], each 48 cols (3 n-tiles), j>=172 -> 0.
// Fragment order: Bpack[((ks*48 + nt)*64 + lane)*8 + e] = B[ks*32+(lane>>4)*8+e][nt*16+(lane&15)]
// ---------------------------------------------------------------------------
__global__ void prep_kernel(const float* __restrict__ wih, const float* __restrict__ whh,
                            const float* __restrict__ bih, const float* __restrict__ bhh,
                            unsigned short* __restrict__ Bpack, float* __restrict__ bias4) {
  int gid = blockIdx.x * 256 + threadIdx.x;
  if (gid < 688) {
    int which = gid / 172, j = gid % 172;
    float v;
    if (which == 0)      v = bih[j]       + bhh[j];        // r
    else if (which == 1) v = bih[172 + j] + bhh[172 + j];  // z
    else if (which == 2) v = bih[344 + j];                 // i_n
    else                 v = bhh[344 + j];                 // h_n
    bias4[gid] = v;
  }
  if (gid >= BPACK_USHORTS) return;
  int e  = gid & 7;
  int l  = (gid >> 3) & 63;
  int nt = (gid >> 9) % NTILES;
  int ks = gid / (512 * NTILES);
  int k  = ks * 32 + ((l >> 4) << 3) + e;
  int c  = l & 15;
  int w  = nt / NT_W, tl = nt % NT_W;
  int gate = tl / 3, ti = tl % 3;
  int j = w * 48 + ti * 16 + c;
  float v = 0.f;
  if (j < D) {
    if (gate == 0) {            // r_pre = i_r + h_r
      if (k < D)        v = wih[j * D + k];
      else if (k < 2*D) v = whh[j * D + (k - D)];
    } else if (gate == 1) {     // z_pre
      if (k < D)        v = wih[(D + j) * D + k];
      else if (k < 2*D) v = whh[(D + j) * D + (k - D)];
    } else if (gate == 2) {     // i_n
      if (k < D)        v = wih[(2*D + j) * D + k];
    } else {                    // h_n
      if (k >= D && k < 2*D) v = whh[(2*D + j) * D + (k - D)];
    }
  }
  Bpack[gid] = f2bf(v);
}

// ---------------------------------------------------------------------------
// Bulk copy: memory -> out (172M f32) and last_update -> out tail (1M f32)
// ---------------------------------------------------------------------------
__global__ void copy_kernel(const float4* __restrict__ mem4, const float4* __restrict__ lu4,
                            float4* __restrict__ out4, float4* __restrict__ outlu4) {
  const long NM4 = (long)N_NODES * D / 4;   // 43,000,000
  const long NL4 = N_NODES / 4;             // 250,000
  long stride = (long)gridDim.x * blockDim.x;
  for (long i = (long)blockIdx.x * blockDim.x + threadIdx.x; i < NM4 + NL4; i += stride) {
    if (i < NM4) out4[i] = mem4[i];
    else         outlu4[i - NM4] = lu4[i - NM4];
  }
}

// ---------------------------------------------------------------------------
// Fused GRU GEMM: per block, 32 rows. A = [x|h] bf16 staged in LDS.
// Wave w computes 2 m-tiles x 12 n-tiles; epilogue does gates + scatter.
// ---------------------------------------------------------------------------
__global__ __launch_bounds__(256, 2)
void gru_kernel(const float* __restrict__ memory, const float* __restrict__ msgs,
                const int* __restrict__ ids, const float* __restrict__ ts,
                const unsigned short* __restrict__ Bpack, const float* __restrict__ bias4,
                float* __restrict__ out_mem, float* __restrict__ out_lu) {
  __shared__ unsigned short At[BM * LDA];
  __shared__ int ids_s[BM];
  const int tid = threadIdx.x;
  const int m0  = blockIdx.x * BM;

  if (tid < BM) {
    int nid = ids[m0 + tid];
    ids_s[tid] = nid;
    out_lu[nid] = ts[m0 + tid];   // runs after copy_kernel in stream order
  }
  __syncthreads();

  // Stage A: per row, 43 float4 of x then 43 float4 of gathered h -> bf16
  for (int idx = tid; idx < BM * 86; idx += 256) {
    int row = idx / 86, seg = idx % 86;
    float4 v; int kk;
    if (seg < 43) {
      v = ((const float4*)(msgs + (size_t)(m0 + row) * D))[seg];
      kk = seg * 4;
    } else {
      int s = seg - 43;
      v = ((const float4*)(memory + (size_t)ids_s[row] * D))[s];
      kk = D + s * 4;
    }
    ushort4 b4 = make_ushort4(f2bf(v.x), f2bf(v.y), f2bf(v.z), f2bf(v.w));
    *(ushort4*)&At[row * LDA + kk] = b4;
  }
  // zero-pad k = 344..359
  for (int idx = tid; idx < BM * 2; idx += 256) {
    int row = idx >> 1, p = idx & 1;
    *(uint4*)&At[row * LDA + 2*D + p * 8] = make_uint4(0, 0, 0, 0);
  }
  __syncthreads();

  const int wave = tid >> 6, lane = tid & 63;
  const int g = lane >> 4, c = lane & 15;

  f32x4 acc[2][NT_W];
  #pragma unroll
  for (int i = 0; i < 2; ++i)
    #pragma unroll
    for (int n2 = 0; n2 < NT_W; ++n2)
      acc[i][n2] = (f32x4){0.f, 0.f, 0.f, 0.f};

  const short8* Bp = (const short8*)Bpack;
  #pragma unroll
  for (int ks = 0; ks < KSTEPS; ++ks) {
    const short8 a0 = *(const short8*)&At[c        * LDA + ks * 32 + g * 8];
    const short8 a1 = *(const short8*)&At[(16 + c) * LDA + ks * 32 + g * 8];
    const short8* bb = Bp + ((size_t)(ks * NTILES + wave * NT_W)) * 64 + lane;
    #pragma unroll
    for (int nt = 0; nt < NT_W; ++nt) {
      short8 b = bb[nt * 64];
      acc[0][nt] = __builtin_amdgcn_mfma_f32_16x16x32_bf16(a0, b, acc[0][nt], 0, 0, 0);
      acc[1][nt] = __builtin_amdgcn_mfma_f32_16x16x32_bf16(a1, b, acc[1][nt], 0, 0, 0);
    }
  }

  // Epilogue: gates + blend + scatter. acc[mt][gate*3+ti][r]
  #pragma unroll
  for (int mt = 0; mt < 2; ++mt) {
    #pragma unroll
    for (int r = 0; r < 4; ++r) {
      int row_local = mt * 16 + g * 4 + r;
      float* orow = out_mem + (size_t)ids_s[row_local] * D;
      #pragma unroll
      for (int ti = 0; ti < 3; ++ti) {
        int j = wave * 48 + ti * 16 + c;
        if (j < D) {
          float rp = acc[mt][ti][r]     + bias4[j];
          float zp = acc[mt][3 + ti][r] + bias4[172 + j];
          float ip = acc[mt][6 + ti][r] + bias4[344 + j];
          float hp = acc[mt][9 + ti][r] + bias4[516 + j];
          float h_old = bf2f(At[row_local * LDA + D + j]);
          float rr = 1.f / (1.f + __expf(-rp));
          float zz = 1.f / (1.f + __expf(-zp));
          float nn = tanhf(ip + rr * hp);
          orow[j] = nn + zz * (h_old - nn);
        }
      }
    }
  }
}

extern "C" void kernel_launch(void* const* d_in, const int* in_sizes, int n_in,
                              void* d_out, int out_size, void* d_ws, size_t ws_size,
                              hipStream_t stream) {
  const float* memory      = (const float*)d_in[0];
  const float* last_update = (const float*)d_in[1];
  const int*   ids         = (const int*)  d_in[2];
  const float* msgs        = (const float*)d_in[3];
  const float* ts          = (const float*)d_in[4];
  const float* wih         = (const float*)d_in[5];
  const float* whh         = (const float*)d_in[6];
  const float* bih         = (const float*)d_in[7];
  const float* bhh         = (const float*)d_in[8];

  float* out_mem = (float*)d_out;
  float* out_lu  = out_mem + (size_t)N_NODES * D;

  unsigned short* Bpack = (unsigned short*)d_ws;
  float* bias4 = (float*)((char*)d_ws + BIAS_OFF_BYTES);

  prep_kernel<<<BPACK_USHORTS / 256, 256, 0, stream>>>(wih, whh, bih, bhh, Bpack, bias4);
  copy_kernel<<<4096, 256, 0, stream>>>((const float4*)memory, (const float4*)last_update,
                                        (float4*)out_mem, (float4*)out_lu);
  gru_kernel<<<N_UPD / BM, 256, 0, stream>>>(memory, msgs, ids, ts, Bpack, bias4,
                                             out_mem, out_lu);
}

// Round 3
// 723.566 us; speedup vs baseline: 1.0653x; 1.0653x over previous
//
#include <hip/hip_runtime.h>

typedef __attribute__((ext_vector_type(8))) short short8;
typedef __attribute__((ext_vector_type(4))) float f32x4;

#define N_NODES 1000000
#define N_UPD   200000
#define D       172
#define BM      32          // rows per GRU block
#define LDA     360         // LDS A row stride in ushorts (720B)
#define KSTEPS  11          // 11 * 32 = 352 >= 344
#define NTILES  48          // 768 padded N cols / 16
#define GRU_BLOCKS (N_UPD / BM)              // 6250
#define PAIR_SLOTS 6256                      // 782 groups of 8 (>= GRU_BLOCKS)
#define TOTAL_BLOCKS (2 * PAIR_SLOTS)        // 12512
#define NM4 43000000                         // N_NODES*D/4 float4s
#define BPACK_USHORTS (KSTEPS*NTILES*64*8)   // 270336
#define BIAS_OFF  (BPACK_USHORTS*2)          // 540672 B
#define MASK_OFF  (BIAS_OFF + 688*4)         // 543424 B (16B aligned)
#define WS_NEED   (MASK_OFF + N_NODES)       // ~1.55 MB

__device__ __forceinline__ unsigned short f2bf(float f) {
  union { float f; unsigned u; } v; v.f = f;
  unsigned r = v.u + 0x7FFFu + ((v.u >> 16) & 1u);
  return (unsigned short)(r >> 16);
}
__device__ __forceinline__ float bf2f(unsigned short h) {
  union { unsigned u; float f; } v; v.u = ((unsigned)h) << 16;
  return v.f;
}

// ---------------------------------------------------------------------------
// Prep: pack B into MFMA-fragment order + fused biases + clear node mask.
// Bpack[((ks*48+nt)*64+lane)*8+e] = B[ks*32+(lane>>4)*8+e][nt*16+(lane&15)]
// col group w=nt/12 owns cols w*48..w*48+48 of [r_pre|z_pre|i_n|h_n].
// ---------------------------------------------------------------------------
__global__ void prep_kernel(const float* __restrict__ wih, const float* __restrict__ whh,
                            const float* __restrict__ bih, const float* __restrict__ bhh,
                            unsigned short* __restrict__ Bpack, float* __restrict__ bias4,
                            uint4* __restrict__ mask16) {
  int gid = blockIdx.x * 256 + threadIdx.x;
  if (gid < 688) {
    int which = gid / 172, j = gid % 172;
    float v;
    if (which == 0)      v = bih[j]       + bhh[j];        // r
    else if (which == 1) v = bih[172 + j] + bhh[172 + j];  // z
    else if (which == 2) v = bih[344 + j];                 // i_n
    else                 v = bhh[344 + j];                 // h_n
    bias4[gid] = v;
  }
  if (gid < N_NODES / 16) mask16[gid] = make_uint4(0, 0, 0, 0);
  if (gid >= BPACK_USHORTS) return;
  int e  = gid & 7;
  int l  = (gid >> 3) & 63;
  int nt = (gid >> 9) % NTILES;
  int ks = gid / (512 * NTILES);
  int k  = ks * 32 + ((l >> 4) << 3) + e;
  int c  = l & 15;
  int w  = nt / 12, tl = nt % 12;
  int gate = tl / 3, ti = tl % 3;
  int j = w * 48 + ti * 16 + c;
  float v = 0.f;
  if (j < D) {
    if (gate == 0) {            // r_pre
      if (k < D)        v = wih[j * D + k];
      else if (k < 2*D) v = whh[j * D + (k - D)];
    } else if (gate == 1) {     // z_pre
      if (k < D)        v = wih[(D + j) * D + k];
      else if (k < 2*D) v = whh[(D + j) * D + (k - D)];
    } else if (gate == 2) {     // i_n
      if (k < D)        v = wih[(2*D + j) * D + k];
    } else {                    // h_n
      if (k >= D && k < 2*D) v = whh[(2*D + j) * D + (k - D)];
    }
  }
  Bpack[gid] = f2bf(v);
}

__global__ void mask_set_kernel(const int* __restrict__ ids, unsigned char* __restrict__ mask) {
  int i = blockIdx.x * 256 + threadIdx.x;
  if (i < N_UPD) mask[ids[i]] = 1;
}

// Fallback full copy (serial path)
__global__ void copy_kernel(const float4* __restrict__ mem4, const float4* __restrict__ lu4,
                            float4* __restrict__ out4, float4* __restrict__ outlu4) {
  const long NL4 = N_NODES / 4;
  long stride = (long)gridDim.x * blockDim.x;
  for (long i = (long)blockIdx.x * blockDim.x + threadIdx.x; i < NM4 + NL4; i += stride) {
    if (i < NM4) out4[i] = mem4[i];
    else         outlu4[i - NM4] = lu4[i - NM4];
  }
}

// ---------------------------------------------------------------------------
// Fused kernel: even 8-groups = GRU blocks (8 waves, named accumulators),
// odd 8-groups = masked copy blocks. Disjoint writes -> no ordering needed.
// ---------------------------------------------------------------------------
template<int FUSED>
__global__ __launch_bounds__(512, 4)
void gru8_kernel(const float* __restrict__ memory, const float* __restrict__ last_update,
                 const float* __restrict__ msgs, const int* __restrict__ ids,
                 const float* __restrict__ ts, const unsigned short* __restrict__ Bpack,
                 const float* __restrict__ bias4, const unsigned char* __restrict__ mask,
                 float* __restrict__ out_mem, float* __restrict__ out_lu) {
  __shared__ unsigned short At[BM * LDA];
  __shared__ int ids_s[BM];
  const int tid = threadIdx.x;
  int idx; bool is_gru;
  if (FUSED) {
    int g8 = blockIdx.x >> 3;
    idx = (g8 >> 1) * 8 + (blockIdx.x & 7);
    is_gru = (g8 & 1) == 0;
  } else { idx = blockIdx.x; is_gru = true; }

  if (!is_gru) {
    // ---- masked copy path ----
    const float4* mem4 = (const float4*)memory;
    float4* out4 = (float4*)out_mem;
    const unsigned tstride = PAIR_SLOTS * 512;
    for (unsigned i = (unsigned)idx * 512 + tid; i < NM4; i += tstride) {
      unsigned row = i / 43u;
      if (!mask[row]) out4[i] = mem4[i];
    }
    for (unsigned j = (unsigned)idx * 512 + tid; j < N_NODES; j += tstride) {
      if (!mask[j]) out_lu[j] = last_update[j];
    }
    return;
  }
  if (idx >= GRU_BLOCKS) return;

  // ---- GRU path ----
  const int m0 = idx * BM;
  if (tid < BM) {
    int nid = ids[m0 + tid];
    ids_s[tid] = nid;
    out_lu[nid] = ts[m0 + tid];     // disjoint from copy path (masked nodes)
  }
  __syncthreads();

  for (int s = tid; s < BM * 86; s += 512) {
    int row = s / 86, seg = s % 86;
    float4 v; int kk;
    if (seg < 43) {
      v = ((const float4*)(msgs + (size_t)(m0 + row) * D))[seg];
      kk = seg * 4;
    } else {
      int s2 = seg - 43;
      v = ((const float4*)(memory + (size_t)ids_s[row] * D))[s2];
      kk = D + s2 * 4;
    }
    *(ushort4*)&At[row * LDA + kk] = make_ushort4(f2bf(v.x), f2bf(v.y), f2bf(v.z), f2bf(v.w));
  }
  if (tid < BM * 2) {   // zero-pad k = 344..359
    int row = tid >> 1, p = tid & 1;
    *(uint4*)&At[row * LDA + 2*D + p * 8] = make_uint4(0, 0, 0, 0);
  }
  __syncthreads();

  const int wave = tid >> 6, lane = tid & 63;
  const int g = lane >> 4, c = lane & 15;
  const int wm = wave >> 2, wc = wave & 3;   // m-tile, column group
  const int arow = wm * 16 + c;

  f32x4 A0 = {0,0,0,0}, A1 = {0,0,0,0}, A2 = {0,0,0,0}, A3 = {0,0,0,0};
  f32x4 A4 = {0,0,0,0}, A5 = {0,0,0,0}, A6 = {0,0,0,0}, A7 = {0,0,0,0};
  f32x4 A8 = {0,0,0,0}, A9 = {0,0,0,0}, A10 = {0,0,0,0}, A11 = {0,0,0,0};

  const short8* Bp = (const short8*)Bpack;
#define MM(Acc, NT) Acc = __builtin_amdgcn_mfma_f32_16x16x32_bf16(a, bb[(NT)*64], Acc, 0, 0, 0)
  #pragma unroll 2
  for (int ks = 0; ks < KSTEPS; ++ks) {
    short8 a = *(const short8*)&At[arow * LDA + ks * 32 + g * 8];
    const short8* bb = Bp + (size_t)((ks * NTILES + wc * 12) * 64 + lane);
    MM(A0, 0);  MM(A1, 1);  MM(A2, 2);  MM(A3, 3);
    MM(A4, 4);  MM(A5, 5);  MM(A6, 6);  MM(A7, 7);
    MM(A8, 8);  MM(A9, 9);  MM(A10, 10); MM(A11, 11);
  }
#undef MM

  #pragma unroll
  for (int r = 0; r < 4; ++r) {
    const int row_local = wm * 16 + g * 4 + r;
    float* orow = out_mem + (size_t)ids_s[row_local] * D;
    const unsigned short* hrow = &At[row_local * LDA + D];
#define DO_TI(TI, Ar, Az, Ai, Ah) { int j = wc * 48 + (TI) * 16 + c; if (j < D) { \
      float rp = Ar[r] + bias4[j];        float zp = Az[r] + bias4[172 + j];      \
      float ip = Ai[r] + bias4[344 + j];  float hp = Ah[r] + bias4[516 + j];      \
      float ho = bf2f(hrow[j]);                                                   \
      float rr = 1.f / (1.f + __expf(-rp));                                       \
      float zz = 1.f / (1.f + __expf(-zp));                                       \
      float e2 = __expf(2.f * (ip + rr * hp));                                    \
      float nn = 1.f - 2.f / (e2 + 1.f);                                          \
      orow[j] = nn + zz * (ho - nn); } }
    DO_TI(0, A0, A3, A6, A9)
    DO_TI(1, A1, A4, A7, A10)
    DO_TI(2, A2, A5, A8, A11)
#undef DO_TI
  }
}

extern "C" void kernel_launch(void* const* d_in, const int* in_sizes, int n_in,
                              void* d_out, int out_size, void* d_ws, size_t ws_size,
                              hipStream_t stream) {
  const float* memory      = (const float*)d_in[0];
  const float* last_update = (const float*)d_in[1];
  const int*   ids         = (const int*)  d_in[2];
  const float* msgs        = (const float*)d_in[3];
  const float* ts          = (const float*)d_in[4];
  const float* wih         = (const float*)d_in[5];
  const float* whh         = (const float*)d_in[6];
  const float* bih         = (const float*)d_in[7];
  const float* bhh         = (const float*)d_in[8];

  float* out_mem = (float*)d_out;
  float* out_lu  = out_mem + (size_t)N_NODES * D;

  unsigned short* Bpack = (unsigned short*)d_ws;
  float* bias4 = (float*)((char*)d_ws + BIAS_OFF);
  unsigned char* mask = (unsigned char*)d_ws + MASK_OFF;

  prep_kernel<<<BPACK_USHORTS / 256, 256, 0, stream>>>(wih, whh, bih, bhh, Bpack, bias4,
                                                       (uint4*)mask);
  if (ws_size >= WS_NEED) {
    mask_set_kernel<<<(N_UPD + 255) / 256, 256, 0, stream>>>(ids, mask);
    gru8_kernel<1><<<TOTAL_BLOCKS, 512, 0, stream>>>(memory, last_update, msgs, ids, ts,
                                                     Bpack, bias4, mask, out_mem, out_lu);
  } else {
    copy_kernel<<<4096, 256, 0, stream>>>((const float4*)memory, (const float4*)last_update,
                                          (float4*)out_mem, (float4*)out_lu);
    gru8_kernel<0><<<GRU_BLOCKS, 512, 0, stream>>>(memory, last_update, msgs, ids, ts,
                                                   Bpack, bias4, mask, out_mem, out_lu);
  }
}